// Round 3
// baseline (358.607 us; speedup 1.0000x reference)
//
#include <hip/hip_runtime.h>
#include <hip/hip_bf16.h>
#include <math.h>

// Problem constants
#define BATCH 4
#define SEQ   2048
#define HID   768
#define INTER 1536
#define DK    128
#define NTOT  3200      // 2*INTER + DK
#define NTOTP 3328      // padded to 13*256 for 256-wide gemm1 tiles
#define MROWS 8192      // BATCH*SEQ
#define LN512 6.2383246250395075f

typedef _Float16 half8   __attribute__((ext_vector_type(8)));
typedef _Float16 half4   __attribute__((ext_vector_type(4)));
typedef float    floatx4 __attribute__((ext_vector_type(4)));
typedef float    floatx16 __attribute__((ext_vector_type(16)));

typedef const __attribute__((address_space(1))) unsigned int* gas1_t;
typedef __attribute__((address_space(3))) unsigned int* las3_t;

static __device__ __forceinline__ void load16(const _Float16* g, _Float16* l) {
    __builtin_amdgcn_global_load_lds((gas1_t)g, (las3_t)l, 16, 0, 0);
}
#define WAIT_VM(N)    asm volatile("s_waitcnt vmcnt(" #N ")" ::: "memory")
#define BARRIER_RAW() asm volatile("s_barrier" ::: "memory")

// ---------------------------------------------------------------- prep kernels
__global__ void cast_h_kernel(const float* __restrict__ in, _Float16* __restrict__ out, int n) {
    int i = (blockIdx.x * blockDim.x + threadIdx.x) * 8;
    if (i < n) {
        float4 a = *reinterpret_cast<const float4*>(in + i);
        float4 b = *reinterpret_cast<const float4*>(in + i + 4);
        half8 h = {(_Float16)a.x, (_Float16)a.y, (_Float16)a.z, (_Float16)a.w,
                   (_Float16)b.x, (_Float16)b.y, (_Float16)b.z, (_Float16)b.w};
        *reinterpret_cast<half8*>(out + i) = h;
    }
}

// pads columns [NTOT, NTOTP) with zeros so gemm1 can use 256-wide N tiles
__global__ void trans_wi_kernel(const float* __restrict__ Wi, _Float16* __restrict__ WiT) {
    __shared__ _Float16 tile[32][33];
    const int c0 = blockIdx.x * 32, r0 = blockIdx.y * 32;
    const int tx = threadIdx.x, ty = threadIdx.y;
#pragma unroll
    for (int j = 0; j < 32; j += 8)
        tile[tx][ty + j] = (c0 + tx < NTOT)
            ? (_Float16)Wi[(size_t)(r0 + ty + j) * NTOT + c0 + tx]
            : (_Float16)0.0f;
    __syncthreads();
#pragma unroll
    for (int j = 0; j < 32; j += 8)
        WiT[(size_t)(c0 + ty + j) * HID + r0 + tx] = tile[ty + j][tx];
}

__global__ void trans_wo_kernel(const float* __restrict__ Wo, _Float16* __restrict__ WoT) {
    __shared__ _Float16 tile[32][33];
    const int c0 = blockIdx.x * 32, r0 = blockIdx.y * 32;
    const int tx = threadIdx.x, ty = threadIdx.y;
#pragma unroll
    for (int j = 0; j < 32; j += 8)
        tile[tx][ty + j] = (_Float16)Wo[(size_t)(r0 + ty + j) * HID + c0 + tx];
    __syncthreads();
#pragma unroll
    for (int j = 0; j < 32; j += 8)
        WoT[(size_t)(c0 + ty + j) * INTER + r0 + tx] = tile[ty + j][tx];
}

__global__ void mask_scales_kernel(const int* __restrict__ mask, float* __restrict__ scales) {
    __shared__ int sh[256];
    int b = blockIdx.x;
    int s = 0;
    for (int i = threadIdx.x; i < SEQ; i += 256) s += mask[b * SEQ + i];
    sh[threadIdx.x] = s;
    __syncthreads();
    for (int off = 128; off > 0; off >>= 1) {
        if (threadIdx.x < off) sh[threadIdx.x] += sh[threadIdx.x + off];
        __syncthreads();
    }
    if (threadIdx.x == 0) scales[b] = logf((float)sh[0]) / LN512;
}

// ---------------------------------------------------------------- shared tile ctx (256-thread kernels)
struct TileCtx {
    int tid, wave, lane, quad, l16, l31, half, wm, wn;
};
static __device__ __forceinline__ TileCtx make_ctx() {
    TileCtx t;
    t.tid = threadIdx.x;
    t.wave = t.tid >> 6; t.lane = t.tid & 63;
    t.quad = t.lane >> 4; t.l16 = t.lane & 15;
    t.l31 = t.lane & 31;  t.half = t.lane >> 5;
    t.wm = (t.wave & 1) * 64;
    t.wn = (t.wave >> 1) * 64;
    return t;
}

// ================================================================ mainloop CM32: 32x32x16 (pv/gemm2)
// Chunk-major LDS: per K-tile, A stored as [4 kchunks][128 rows][8 f16] (B same).
// Fragment reads = 64 lanes contiguous bytes -> provably bank-conflict-free, no
// swizzle. Staging linear in tid (chunk j <-> LDS off j*16B; global = row*ld +
// chunk*8). 4 slots (64KB), distance-3 prefetch, ONE barrier + counted vmcnt(8)
// per K-tile, setprio around MFMA. Safety: stage at iter k targets slot
// (k-1)&3, last read at k-1 and protected by k-1's closing barrier (every
// ds_read is consumed by an MFMA first -> compiler lgkmcnt covers completion);
// reads at k are covered by k-1's vmcnt(8)+barrier.
static __device__ __forceinline__ void gemm_mainloop_cm32(
    const TileCtx& t,
    const _Float16* __restrict__ Ag, int lda,
    const _Float16* __restrict__ Bg, int ldb,
    int K, _Float16* smem, floatx16 acc[2][2])
{
    const int rst = t.tid & 127;          // staged row
    const int c08 = (t.tid >> 7) * 8;     // first chunk col offset (f16)
    const _Float16* pa = Ag + (size_t)rst * lda + c08;
    const _Float16* pb = Bg + (size_t)rst * ldb + c08;
    const int nKt = K >> 5;

    // fragment base offsets (f16 units): chunk = h*2 + half
    const int arow = t.wm + t.l31;        // + mt*32
    const int brow = t.wn + t.l31;        // + nt*32

    // prologue: tiles 0..2 -> slots 0..2
#pragma unroll
    for (int pt = 0; pt < 3; ++pt) {
        _Float16* ld = smem + pt * 8192 + t.tid * 8;
        const int ko = pt * 32;
        load16(pa + ko,      ld);
        load16(pa + ko + 16, ld + 2048);
        load16(pb + ko,      ld + 4096);
        load16(pb + ko + 16, ld + 6144);
    }
    WAIT_VM(8);        // tile 0 landed
    BARRIER_RAW();

    for (int k = 0; k < nKt; ++k) {
        const _Float16* Ab = smem + (k & 3) * 8192;
        const _Float16* Bb = Ab + 4096;
        if (k + 3 < nKt) {
            _Float16* ld = smem + ((k + 3) & 3) * 8192 + t.tid * 8;
            const int ko = (k + 3) * 32;
            load16(pa + ko,      ld);
            load16(pa + ko + 16, ld + 2048);
            load16(pb + ko,      ld + 4096);
            load16(pb + ko + 16, ld + 6144);
        }
        half8 af[2][2], bf[2][2];   // [tile][kstep]
#pragma unroll
        for (int mt = 0; mt < 2; ++mt)
#pragma unroll
            for (int h = 0; h < 2; ++h)
                af[mt][h] = *reinterpret_cast<const half8*>(
                    Ab + (h * 2 + t.half) * 1024 + (arow + mt * 32) * 8);
#pragma unroll
        for (int nt = 0; nt < 2; ++nt)
#pragma unroll
            for (int h = 0; h < 2; ++h)
                bf[nt][h] = *reinterpret_cast<const half8*>(
                    Bb + (h * 2 + t.half) * 1024 + (brow + nt * 32) * 8);
        __builtin_amdgcn_s_setprio(1);
#pragma unroll
        for (int h = 0; h < 2; ++h)
#pragma unroll
            for (int mt = 0; mt < 2; ++mt)
#pragma unroll
                for (int nt = 0; nt < 2; ++nt)
                    acc[mt][nt] = __builtin_amdgcn_mfma_f32_32x32x16_f16(af[mt][h], bf[nt][h], acc[mt][nt], 0, 0, 0);
        __builtin_amdgcn_s_setprio(0);
        if (k <= nKt - 4)      { WAIT_VM(8); }
        else if (k == nKt - 3) { WAIT_VM(4); }
        else if (k == nKt - 2) { WAIT_VM(0); }
        BARRIER_RAW();
    }
}

// ---------------------------------------------------------------- GEMM1: silu(H@Wi) -> u, vT, q, k
// 256x256 tile, 512 threads (8 waves 2Mx4N), wave tile 128x64, BK=32,
// 4 LDS slots (128KB) distance-3 prefetch, ONE barrier + counted vmcnt(8) per
// K-tile. Grid 416 = 8 XCD x 4 Mtile x 13 Ntile.
__global__ __launch_bounds__(512, 2) void gemm1_kernel(
    const _Float16* __restrict__ Hb, const _Float16* __restrict__ WiT,
    const float* __restrict__ qg, const float* __restrict__ kg,
    _Float16* __restrict__ u, _Float16* __restrict__ vT,
    _Float16* __restrict__ q, _Float16* __restrict__ k)
{
    __shared__ _Float16 smem[65536];   // 4 slots x 32KB (A 16KB + B 16KB)
    const int tid = threadIdx.x;
    const int lane = tid & 63, wave = tid >> 6;
    const int quad = lane >> 4, l16 = lane & 15;
    const int wm = wave >> 2, wn = wave & 3;          // 2M x 4N waves

    const int f = blockIdx.x;
    const int xcd = f & 7, i = f >> 3;                // i: 0..51
    const int m0 = (xcd * 4 + (i & 3)) * 256;
    const int ntile = i >> 2;                         // 0..12
    const int n0 = ntile * 256;

    const _Float16* Ag = Hb  + (size_t)m0 * HID;
    const _Float16* Bg = WiT + (size_t)n0 * HID;

    const int rA = tid >> 2;
    const int csw = ((tid & 3) ^ ((rA >> 1) & 3)) * 8;
    const _Float16* pa0 = Ag + (size_t)rA * HID + csw;
    const _Float16* pa1 = pa0 + (size_t)128 * HID;
    const _Float16* pb0 = Bg + (size_t)rA * HID + csw;
    const _Float16* pb1 = pb0 + (size_t)128 * HID;

    const int sw8 = (l16 >> 1) & 3;
    const int qs  = (quad ^ sw8) * 8;
    const int aoff = (wm * 128 + l16) * 32 + qs;
    const int boff = 8192 + (wn * 64 + l16) * 32 + qs;

    floatx4 acc[8][4] = {};

    const int nKt = HID / 32;   // 24

    // prologue: stage tiles 0..2 into slots 0..2
#pragma unroll
    for (int pt = 0; pt < 3; ++pt) {
        _Float16* ld = smem + pt * 16384 + tid * 8;
        const int ko = pt * 32;
        load16(pa0 + ko, ld);
        load16(pa1 + ko, ld + 4096);
        load16(pb0 + ko, ld + 8192);
        load16(pb1 + ko, ld + 12288);
    }
    WAIT_VM(8);
    BARRIER_RAW();

    for (int t = 0; t < nKt; ++t) {
        const _Float16* sl = smem + (t & 3) * 16384;
        if (t + 3 < nKt) {
            _Float16* ld = smem + ((t + 3) & 3) * 16384 + tid * 8;
            const int ko = (t + 3) * 32;
            load16(pa0 + ko, ld);        load16(pa1 + ko, ld + 4096);
            load16(pb0 + ko, ld + 8192); load16(pb1 + ko, ld + 12288);
        }
        half8 af[8], bf[4];
#pragma unroll
        for (int mt = 0; mt < 8; ++mt)
            af[mt] = *reinterpret_cast<const half8*>(sl + aoff + mt * 512);
#pragma unroll
        for (int nt = 0; nt < 4; ++nt)
            bf[nt] = *reinterpret_cast<const half8*>(sl + boff + nt * 512);
        __builtin_amdgcn_s_setprio(1);
#pragma unroll
        for (int mt = 0; mt < 8; ++mt)
#pragma unroll
            for (int nt = 0; nt < 4; ++nt)
                acc[mt][nt] = __builtin_amdgcn_mfma_f32_16x16x32_f16(af[mt], bf[nt], acc[mt][nt], 0, 0, 0);
        __builtin_amdgcn_s_setprio(0);
        if (t <= nKt - 4)      { WAIT_VM(8); }
        else if (t == nKt - 3) { WAIT_VM(4); }
        else if (t == nKt - 2) { WAIT_VM(0); }
        BARRIER_RAW();
    }
    __syncthreads();

    // ---------------- epilogue: silu + region-specific stores
    if (ntile < 6) {
#pragma unroll
        for (int mt = 0; mt < 8; ++mt) {
#pragma unroll
            for (int nt = 0; nt < 4; ++nt) {
                const int col = n0 + wn * 64 + nt * 16 + l16;
#pragma unroll
                for (int i2 = 0; i2 < 4; ++i2) {
                    const int row = m0 + wm * 128 + mt * 16 + quad * 4 + i2;
                    float x = acc[mt][nt][i2];
                    float y = x / (1.0f + __expf(-x));
                    u[(size_t)row * INTER + col] = (_Float16)y;
                }
            }
        }
    } else if (ntile < 12) {
        const int bb = m0 >> 11, sloc = m0 & (SEQ - 1), cI = n0 - INTER;
#pragma unroll
        for (int mt = 0; mt < 8; ++mt) {
#pragma unroll
            for (int nt = 0; nt < 4; ++nt) {
                const int cl  = wn * 64 + nt * 16 + l16;
                const int rl0 = wm * 128 + mt * 16 + quad * 4;
                half4 pk;
#pragma unroll
                for (int i2 = 0; i2 < 4; ++i2) {
                    float x = acc[mt][nt][i2];
                    pk[i2] = (_Float16)(x / (1.0f + __expf(-x)));
                }
                *reinterpret_cast<half4*>(smem + cl * 256 + (rl0 ^ ((cl & 31) << 3))) = pk;
            }
        }
        __syncthreads();
#pragma unroll
        for (int p = 0; p < 16; ++p) {
            const int chunk = p * 512 + tid;
            const int cl = chunk >> 5, scn = chunk & 31;
            half8 v = *reinterpret_cast<const half8*>(smem + cl * 256 + ((scn ^ (cl & 31)) << 3));
            *reinterpret_cast<half8*>(vT + ((size_t)bb * INTER + cI + cl) * SEQ + sloc + scn * 8) = v;
        }
    } else {
        if (wn < 2) {
#pragma unroll
            for (int mt = 0; mt < 8; ++mt) {
#pragma unroll
                for (int nt = 0; nt < 4; ++nt) {
                    const int cq = wn * 64 + nt * 16 + l16;
                    const float qgv = qg[cq], kgv = kg[cq];
#pragma unroll
                    for (int i2 = 0; i2 < 4; ++i2) {
                        const int row = m0 + wm * 128 + mt * 16 + quad * 4 + i2;
                        float x = acc[mt][nt][i2];
                        float y = x / (1.0f + __expf(-x));
                        q[(size_t)row * DK + cq] = (_Float16)(y * qgv);
                        k[(size_t)row * DK + cq] = (_Float16)(y * kgv);
                    }
                }
            }
        }
    }
}

// ---------------------------------------------------------------- scores + softmax -> P (f16)
__global__ __launch_bounds__(256) void scores_kernel(
    const _Float16* __restrict__ q, const _Float16* __restrict__ k,
    const int* __restrict__ mask, const float* __restrict__ scales,
    _Float16* __restrict__ P)
{
    const int f = blockIdx.x;
    const int xcd = f & 7, i = f >> 3;          // i: 0..63
    const int b = xcd >> 1;
    const int m0 = ((xcd & 1) * 64 + i) * 16;
    const int tid = threadIdx.x;
    const int wave = tid >> 6, lane = tid & 63, quad = lane >> 4, l16 = lane & 15;
    const float scale = scales[b];

    half8 aq[4];
    const _Float16* qrow = q + (b * SEQ + m0 + l16) * DK + quad * 8;
#pragma unroll
    for (int kk = 0; kk < 4; ++kk) aq[kk] = *reinterpret_cast<const half8*>(qrow + kk * 32);

    floatx4 sc[32];
#pragma unroll
    for (int nt = 0; nt < 32; ++nt) {
        int n0 = nt * 64 + wave * 16;
        const _Float16* krow = k + (b * SEQ + n0 + l16) * DK + quad * 8;
        floatx4 acc = {};
#pragma unroll
        for (int kk = 0; kk < 4; ++kk) {
            half8 bq = *reinterpret_cast<const half8*>(krow + kk * 32);
            acc = __builtin_amdgcn_mfma_f32_16x16x32_f16(aq[kk], bq, acc, 0, 0, 0);
        }
        sc[nt] = acc;
    }

    const float rs = 0.08838834764831845f * scale;
    const float mval = -1e12f * scale;
    float rmax[4] = {-3.4e38f, -3.4e38f, -3.4e38f, -3.4e38f};
#pragma unroll
    for (int nt = 0; nt < 32; ++nt) {
        int ncol = nt * 64 + wave * 16 + l16;
        bool mok = mask[b * SEQ + ncol] != 0;
#pragma unroll
        for (int i2 = 0; i2 < 4; ++i2) {
            float s = mok ? sc[nt][i2] * rs : mval;
            sc[nt][i2] = s;
            rmax[i2] = fmaxf(rmax[i2], s);
        }
    }
#pragma unroll
    for (int i2 = 0; i2 < 4; ++i2) {
#pragma unroll
        for (int off = 1; off < 16; off <<= 1)
            rmax[i2] = fmaxf(rmax[i2], __shfl_xor(rmax[i2], off, 64));
    }
    __shared__ float redmax[4][16];
    __shared__ float redsum[4][16];
    if (l16 == 0) {
#pragma unroll
        for (int i2 = 0; i2 < 4; ++i2) redmax[wave][quad * 4 + i2] = rmax[i2];
    }
    __syncthreads();
#pragma unroll
    for (int i2 = 0; i2 < 4; ++i2) {
        int r = quad * 4 + i2;
        rmax[i2] = fmaxf(fmaxf(redmax[0][r], redmax[1][r]), fmaxf(redmax[2][r], redmax[3][r]));
    }
    float rsum[4] = {0.f, 0.f, 0.f, 0.f};
#pragma unroll
    for (int nt = 0; nt < 32; ++nt) {
#pragma unroll
        for (int i2 = 0; i2 < 4; ++i2) {
            float e = __expf(sc[nt][i2] - rmax[i2]);
            sc[nt][i2] = e;
            rsum[i2] += e;
        }
    }
#pragma unroll
    for (int i2 = 0; i2 < 4; ++i2) {
#pragma unroll
        for (int off = 1; off < 16; off <<= 1) rsum[i2] += __shfl_xor(rsum[i2], off, 64);
    }
    if (l16 == 0) {
#pragma unroll
        for (int i2 = 0; i2 < 4; ++i2) redsum[wave][quad * 4 + i2] = rsum[i2];
    }
    __syncthreads();
#pragma unroll
    for (int i2 = 0; i2 < 4; ++i2) {
        int r = quad * 4 + i2;
        float tot = redsum[0][r] + redsum[1][r] + redsum[2][r] + redsum[3][r];
        float inv = 1.0f / tot;
        int row = m0 + r;
        _Float16* Prow = P + ((size_t)b * SEQ + row) * SEQ;
#pragma unroll
        for (int nt = 0; nt < 32; ++nt) {
            int ncol = nt * 64 + wave * 16 + l16;
            Prow[ncol] = (_Float16)(sc[nt][i2] * inv);
        }
    }
}

// ---------------------------------------------------------------- PV: u <- u .* (P @ v)  (32x32 MFMA, chunk-major)
__global__ __launch_bounds__(256) void pv_kernel(
    const _Float16* __restrict__ P, const _Float16* __restrict__ vT,
    _Float16* __restrict__ u)
{
    __shared__ _Float16 smem[32768];   // 4 slots x 16KB
    TileCtx t = make_ctx();
    const int f = blockIdx.x;
    const int xcd = f & 7, i = f >> 3;
    const int b = i / 24, j = i % 24;
    const int m0 = (xcd * 2 + (j & 1)) * 128;
    const int n0 = (j >> 1) * 128;
    const _Float16* Pb  = P  + (size_t)b * SEQ * SEQ;
    const _Float16* vTb = vT + (size_t)b * INTER * SEQ;

    floatx16 acc[2][2] = {};
    gemm_mainloop_cm32(t, Pb + (size_t)m0 * SEQ, SEQ, vTb + (size_t)n0 * SEQ, SEQ, SEQ, smem, acc);

    // C/D 32x32: col = lane&31, row = (reg&3) + 8*(reg>>2) + 4*(lane>>5)
#pragma unroll
    for (int mt = 0; mt < 2; ++mt) {
#pragma unroll
        for (int nt = 0; nt < 2; ++nt) {
            int col = n0 + t.wn + nt * 32 + t.l31;
#pragma unroll
            for (int reg = 0; reg < 16; ++reg) {
                int row = m0 + t.wm + mt * 32 + (reg & 3) + 8 * (reg >> 2) + 4 * t.half;
                size_t gidx = ((size_t)(b * SEQ + row)) * INTER + col;
                float uv = (float)u[gidx];
                u[gidx] = (_Float16)(acc[mt][nt][reg] * uv);
            }
        }
    }
}

// ---------------------------------------------------------------- GEMM2: out = t @ Wo (fp32 out, 32x32 MFMA, chunk-major)
__global__ __launch_bounds__(256) void gemm2_kernel(
    const _Float16* __restrict__ tin, const _Float16* __restrict__ WoT,
    float* __restrict__ out)
{
    __shared__ _Float16 smem[32768];
    TileCtx t = make_ctx();
    const int f = blockIdx.x;
    const int xcd = f & 7, i = f >> 3;
    const int m0 = ((xcd << 3) | (i & 7)) * 128;
    const int n0 = (i >> 3) * 128;

    floatx16 acc[2][2] = {};
    gemm_mainloop_cm32(t, tin + (size_t)m0 * INTER, INTER, WoT + (size_t)n0 * INTER, INTER, INTER, smem, acc);

#pragma unroll
    for (int mt = 0; mt < 2; ++mt) {
#pragma unroll
        for (int nt = 0; nt < 2; ++nt) {
            int col = n0 + t.wn + nt * 32 + t.l31;
#pragma unroll
            for (int reg = 0; reg < 16; ++reg) {
                int row = m0 + t.wm + mt * 32 + (reg & 3) + 8 * (reg >> 2) + 4 * t.half;
                out[(size_t)row * HID + col] = acc[mt][nt][reg];
            }
        }
    }
}

// ---------------------------------------------------------------- launch
extern "C" void kernel_launch(void* const* d_in, const int* in_sizes, int n_in,
                              void* d_out, int out_size, void* d_ws, size_t ws_size,
                              hipStream_t stream) {
    const float* H    = (const float*)d_in[0];
    const float* Wi   = (const float*)d_in[1];
    const float* Wo   = (const float*)d_in[2];
    const float* qg   = (const float*)d_in[3];
    const float* kg   = (const float*)d_in[4];
    const int*   mask = (const int*)d_in[5];
    float* out = (float*)d_out;

    char* base = (char*)d_ws;
    size_t off = 0;
    auto alloc = [&](size_t bytes) { void* p = base + off; off = (off + bytes + 255) & ~(size_t)255; return p; };
    _Float16* Hb   = (_Float16*)alloc((size_t)MROWS * HID * 2);
    _Float16* WiT  = (_Float16*)alloc((size_t)NTOTP * HID * 2);   // padded rows [NTOT,NTOTP) = 0
    _Float16* WoT  = (_Float16*)alloc((size_t)HID * INTER * 2);
    _Float16* u    = (_Float16*)alloc((size_t)MROWS * INTER * 2);   // becomes t in-place after pv
    _Float16* vT   = (_Float16*)alloc((size_t)BATCH * INTER * SEQ * 2);
    _Float16* q    = (_Float16*)alloc((size_t)MROWS * DK * 2);
    _Float16* k    = (_Float16*)alloc((size_t)MROWS * DK * 2);
    _Float16* P    = (_Float16*)alloc((size_t)BATCH * SEQ * SEQ * 2);
    float*    scales = (float*)alloc(4 * sizeof(float));

    {
        int n = MROWS * HID;
        cast_h_kernel<<<n / 8 / 256, 256, 0, stream>>>(H, Hb, n);
        trans_wi_kernel<<<dim3(NTOTP / 32, HID / 32), dim3(32, 8), 0, stream>>>(Wi, WiT);
        trans_wo_kernel<<<dim3(HID / 32, INTER / 32), dim3(32, 8), 0, stream>>>(Wo, WoT);
        mask_scales_kernel<<<BATCH, 256, 0, stream>>>(mask, scales);
    }
    // GEMM1: M=8192 N=3328(padded) K=768, 256x256 tiles, 8 XCD x 4 M x 13 N
    gemm1_kernel<<<416, 512, 0, stream>>>(Hb, WiT, qg, kg, u, vT, q, k);
    // scores + softmax -> P
    scores_kernel<<<512, 256, 0, stream>>>(q, k, mask, scales, P);
    // PV: per batch M=2048 N=1536 K=2048
    pv_kernel<<<768, 256, 0, stream>>>(P, vT, u);
    // GEMM2: M=8192 N=768 K=1536
    gemm2_kernel<<<384, 256, 0, stream>>>(u, WoT, out);
}

// Round 4
// 296.488 us; speedup vs baseline: 1.2095x; 1.2095x over previous
//
#include <hip/hip_runtime.h>
#include <hip/hip_bf16.h>
#include <math.h>

// Problem constants
#define BATCH 4
#define SEQ   2048
#define HID   768
#define INTER 1536
#define DK    128
#define NTOT  3200      // 2*INTER + DK
#define NTOTP 3328      // padded to 13*256 for 256-wide gemm1 tiles
#define MROWS 8192      // BATCH*SEQ
#define LN512 6.2383246250395075f

typedef _Float16 half8   __attribute__((ext_vector_type(8)));
typedef _Float16 half4   __attribute__((ext_vector_type(4)));
typedef float    floatx4 __attribute__((ext_vector_type(4)));
typedef float    floatx16 __attribute__((ext_vector_type(16)));

typedef const __attribute__((address_space(1))) unsigned int* gas1_t;
typedef __attribute__((address_space(3))) unsigned int* las3_t;

static __device__ __forceinline__ void load16(const _Float16* g, _Float16* l) {
    __builtin_amdgcn_global_load_lds((gas1_t)g, (las3_t)l, 16, 0, 0);
}
#define WAIT_VM(N)    asm volatile("s_waitcnt vmcnt(" #N ")" ::: "memory")
#define WAIT_LGKM0()  asm volatile("s_waitcnt lgkmcnt(0)" ::: "memory")
#define BARRIER_RAW() asm volatile("s_barrier" ::: "memory")

// ---------------------------------------------------------------- merged prep kernel
// grid 6724 = 3072 (cast H) + 2496 (trans Wi) + 1152 (trans Wo) + 4 (mask scales)
__global__ __launch_bounds__(256) void prep_kernel(
    const float* __restrict__ H, _Float16* __restrict__ Hb,
    const float* __restrict__ Wi, _Float16* __restrict__ WiT,
    const float* __restrict__ Wo, _Float16* __restrict__ WoT,
    const int* __restrict__ mask, float* __restrict__ scales)
{
    __shared__ _Float16 tile[32][33];
    __shared__ int sh[256];
    const int bid = blockIdx.x, tid = threadIdx.x;
    if (bid < 3072) {
        // cast H f32 -> f16 (6291456 elems = 3072*256*8 exact)
        const int i = (bid * 256 + tid) * 8;
        float4 a = *reinterpret_cast<const float4*>(H + i);
        float4 b = *reinterpret_cast<const float4*>(H + i + 4);
        half8 h = {(_Float16)a.x, (_Float16)a.y, (_Float16)a.z, (_Float16)a.w,
                   (_Float16)b.x, (_Float16)b.y, (_Float16)b.z, (_Float16)b.w};
        *reinterpret_cast<half8*>(Hb + i) = h;
    } else if (bid < 3072 + 2496) {
        // transpose Wi [768][3200] -> WiT [3328][768], pad cols >= NTOT with 0
        const int l = bid - 3072;
        const int c0 = (l % 104) * 32, r0 = (l / 104) * 32;
        const int tx = tid & 31, ty = tid >> 5;
#pragma unroll
        for (int j = 0; j < 32; j += 8)
            tile[tx][ty + j] = (c0 + tx < NTOT)
                ? (_Float16)Wi[(size_t)(r0 + ty + j) * NTOT + c0 + tx]
                : (_Float16)0.0f;
        __syncthreads();
#pragma unroll
        for (int j = 0; j < 32; j += 8)
            WiT[(size_t)(c0 + ty + j) * HID + r0 + tx] = tile[ty + j][tx];
    } else if (bid < 3072 + 2496 + 1152) {
        // transpose Wo [1536][768] -> WoT [768][1536]
        const int l = bid - (3072 + 2496);
        const int c0 = (l % 24) * 32, r0 = (l / 24) * 32;
        const int tx = tid & 31, ty = tid >> 5;
#pragma unroll
        for (int j = 0; j < 32; j += 8)
            tile[tx][ty + j] = (_Float16)Wo[(size_t)(r0 + ty + j) * HID + c0 + tx];
        __syncthreads();
#pragma unroll
        for (int j = 0; j < 32; j += 8)
            WoT[(size_t)(c0 + ty + j) * INTER + r0 + tx] = tile[ty + j][tx];
    } else {
        // mask row-sums -> log(l)/log(512)
        const int b = bid - (3072 + 2496 + 1152);
        int s = 0;
        for (int i = tid; i < SEQ; i += 256) s += mask[b * SEQ + i];
        sh[tid] = s;
        __syncthreads();
        for (int off = 128; off > 0; off >>= 1) {
            if (tid < off) sh[tid] += sh[tid + off];
            __syncthreads();
        }
        if (tid == 0) scales[b] = logf((float)sh[0]) / LN512;
    }
}

// ---------------------------------------------------------------- shared tile ctx (256-thread kernels)
struct TileCtx {
    int tid, wave, lane, quad, l16, l31, half, wm, wn, c0, c1;
};
static __device__ __forceinline__ TileCtx make_ctx() {
    TileCtx t;
    t.tid = threadIdx.x;
    t.wave = t.tid >> 6; t.lane = t.tid & 63;
    t.quad = t.lane >> 4; t.l16 = t.lane & 15;
    t.l31 = t.lane & 31;  t.half = t.lane >> 5;
    t.wm = (t.wave & 1) * 64;
    t.wn = (t.wave >> 1) * 64;
    t.c0 = t.tid;
    t.c1 = t.tid + 256;
    return t;
}

// ================================================================ mainloop B: 32x32x16 (pv/gemm2)
// R2-proven: 3-slot/48KB/1-barrier skeleton; swizzle s32(r) = ((r>>1)^(r>>3))&3.
static __device__ __forceinline__ void gemm_mainloop_3s32(
    const TileCtx& t,
    const _Float16* __restrict__ Ag, int lda,
    const _Float16* __restrict__ Bg, int ldb,
    int K, _Float16* smem, floatx16 acc[2][2])
{
    const int r0i = t.c0 >> 2, s0 = (((r0i >> 1) ^ (r0i >> 3)) & 3);
    const int r1i = t.c1 >> 2, s1 = (((r1i >> 1) ^ (r1i >> 3)) & 3);
    const int ak0 = ((t.c0 & 3) ^ s0) * 8;
    const int ak1 = ((t.c1 & 3) ^ s1) * 8;
    const _Float16* a0 = Ag + (size_t)r0i * lda + ak0;
    const _Float16* a1 = Ag + (size_t)r1i * lda + ak1;
    const _Float16* b0 = Bg + (size_t)r0i * ldb + ak0;
    const _Float16* b1 = Bg + (size_t)r1i * ldb + ak1;
    _Float16* Asl = smem + t.c0 * 8;
    _Float16* Bsl = smem + 12288 + t.c0 * 8;
    const int nIter = K >> 5;

    const int fsw = ((t.l31 >> 1) ^ (t.l31 >> 3)) & 3;

    load16(a0, Asl);        load16(a1, Asl + 2048);
    load16(b0, Bsl);        load16(b1, Bsl + 2048);
    if (nIter > 1) {
        load16(a0 + 32, Asl + 4096); load16(a1 + 32, Asl + 6144);
        load16(b0 + 32, Bsl + 4096); load16(b1 + 32, Bsl + 6144);
    }

    int sc = 0, sp = 2;
    for (int k = 0; k < nIter; ++k) {
        if (k + 1 < nIter) { WAIT_VM(4); } else { WAIT_VM(0); }
        BARRIER_RAW();
        if (k + 2 < nIter) {
            const int off = sp * 4096;
            const int k0 = (k + 2) << 5;
            load16(a0 + k0, Asl + off); load16(a1 + k0, Asl + off + 2048);
            load16(b0 + k0, Bsl + off); load16(b1 + k0, Bsl + off + 2048);
        }
        const _Float16* Ab = smem + sc * 4096;
        const _Float16* Bb = smem + 12288 + sc * 4096;
        half8 af[2][2], bf[2][2];   // [tile][kstep]
#pragma unroll
        for (int mt = 0; mt < 2; ++mt)
#pragma unroll
            for (int h = 0; h < 2; ++h)
                af[mt][h] = *reinterpret_cast<const half8*>(
                    Ab + (t.wm + mt * 32 + t.l31) * 32 + (((h * 2 + t.half) ^ fsw) * 8));
#pragma unroll
        for (int nt = 0; nt < 2; ++nt)
#pragma unroll
            for (int h = 0; h < 2; ++h)
                bf[nt][h] = *reinterpret_cast<const half8*>(
                    Bb + (t.wn + nt * 32 + t.l31) * 32 + (((h * 2 + t.half) ^ fsw) * 8));
#pragma unroll
        for (int h = 0; h < 2; ++h)
#pragma unroll
            for (int mt = 0; mt < 2; ++mt)
#pragma unroll
                for (int nt = 0; nt < 2; ++nt)
                    acc[mt][nt] = __builtin_amdgcn_mfma_f32_32x32x16_f16(af[mt][h], bf[nt][h], acc[mt][nt], 0, 0, 0);
        WAIT_LGKM0();
        sc = (sc == 2) ? 0 : sc + 1;
        sp = (sp == 2) ? 0 : sp + 1;
    }
}

// ---------------------------------------------------------------- GEMM1: silu(H@Wi) -> u, vT, q, k
// 256x256 tile, 512 threads (8 waves 2Mx4N), wave tile 128x64, BK=32,
// 4 LDS slots (128KB) distance-3 prefetch, ONE barrier + counted vmcnt(8) per
// K-tile. Grid 416 = 8 XCD x 4 Mtile x 13 Ntile.
__global__ __launch_bounds__(512, 2) void gemm1_kernel(
    const _Float16* __restrict__ Hb, const _Float16* __restrict__ WiT,
    const float* __restrict__ qg, const float* __restrict__ kg,
    _Float16* __restrict__ u, _Float16* __restrict__ vT,
    _Float16* __restrict__ q, _Float16* __restrict__ k)
{
    __shared__ _Float16 smem[65536];   // 4 slots x 32KB (A 16KB + B 16KB)
    const int tid = threadIdx.x;
    const int lane = tid & 63, wave = tid >> 6;
    const int quad = lane >> 4, l16 = lane & 15;
    const int wm = wave >> 2, wn = wave & 3;          // 2M x 4N waves

    const int f = blockIdx.x;
    const int xcd = f & 7, i = f >> 3;                // i: 0..51
    const int m0 = (xcd * 4 + (i & 3)) * 256;
    const int ntile = i >> 2;                         // 0..12
    const int n0 = ntile * 256;

    const _Float16* Ag = Hb  + (size_t)m0 * HID;
    const _Float16* Bg = WiT + (size_t)n0 * HID;

    const int rA = tid >> 2;
    const int csw = ((tid & 3) ^ ((rA >> 1) & 3)) * 8;
    const _Float16* pa0 = Ag + (size_t)rA * HID + csw;
    const _Float16* pa1 = pa0 + (size_t)128 * HID;
    const _Float16* pb0 = Bg + (size_t)rA * HID + csw;
    const _Float16* pb1 = pb0 + (size_t)128 * HID;

    const int sw8 = (l16 >> 1) & 3;
    const int qs  = (quad ^ sw8) * 8;
    const int aoff = (wm * 128 + l16) * 32 + qs;
    const int boff = 8192 + (wn * 64 + l16) * 32 + qs;

    floatx4 acc[8][4] = {};

    const int nKt = HID / 32;   // 24

    // prologue: stage tiles 0..2 into slots 0..2
#pragma unroll
    for (int pt = 0; pt < 3; ++pt) {
        _Float16* ld = smem + pt * 16384 + tid * 8;
        const int ko = pt * 32;
        load16(pa0 + ko, ld);
        load16(pa1 + ko, ld + 4096);
        load16(pb0 + ko, ld + 8192);
        load16(pb1 + ko, ld + 12288);
    }
    WAIT_VM(8);
    BARRIER_RAW();

    for (int t = 0; t < nKt; ++t) {
        const _Float16* sl = smem + (t & 3) * 16384;
        if (t + 3 < nKt) {
            _Float16* ld = smem + ((t + 3) & 3) * 16384 + tid * 8;
            const int ko = (t + 3) * 32;
            load16(pa0 + ko, ld);        load16(pa1 + ko, ld + 4096);
            load16(pb0 + ko, ld + 8192); load16(pb1 + ko, ld + 12288);
        }
        half8 af[8], bf[4];
#pragma unroll
        for (int mt = 0; mt < 8; ++mt)
            af[mt] = *reinterpret_cast<const half8*>(sl + aoff + mt * 512);
#pragma unroll
        for (int nt = 0; nt < 4; ++nt)
            bf[nt] = *reinterpret_cast<const half8*>(sl + boff + nt * 512);
        __builtin_amdgcn_s_setprio(1);
#pragma unroll
        for (int mt = 0; mt < 8; ++mt)
#pragma unroll
            for (int nt = 0; nt < 4; ++nt)
                acc[mt][nt] = __builtin_amdgcn_mfma_f32_16x16x32_f16(af[mt], bf[nt], acc[mt][nt], 0, 0, 0);
        __builtin_amdgcn_s_setprio(0);
        if (t <= nKt - 4)      { WAIT_VM(8); }
        else if (t == nKt - 3) { WAIT_VM(4); }
        else if (t == nKt - 2) { WAIT_VM(0); }
        BARRIER_RAW();
    }
    __syncthreads();

    // ---------------- epilogue: silu + region-specific stores
    if (ntile < 6) {
#pragma unroll
        for (int mt = 0; mt < 8; ++mt) {
#pragma unroll
            for (int nt = 0; nt < 4; ++nt) {
                const int col = n0 + wn * 64 + nt * 16 + l16;
#pragma unroll
                for (int i2 = 0; i2 < 4; ++i2) {
                    const int row = m0 + wm * 128 + mt * 16 + quad * 4 + i2;
                    float x = acc[mt][nt][i2];
                    float y = x / (1.0f + __expf(-x));
                    u[(size_t)row * INTER + col] = (_Float16)y;
                }
            }
        }
    } else if (ntile < 12) {
        const int bb = m0 >> 11, sloc = m0 & (SEQ - 1), cI = n0 - INTER;
#pragma unroll
        for (int mt = 0; mt < 8; ++mt) {
#pragma unroll
            for (int nt = 0; nt < 4; ++nt) {
                const int cl  = wn * 64 + nt * 16 + l16;
                const int rl0 = wm * 128 + mt * 16 + quad * 4;
                half4 pk;
#pragma unroll
                for (int i2 = 0; i2 < 4; ++i2) {
                    float x = acc[mt][nt][i2];
                    pk[i2] = (_Float16)(x / (1.0f + __expf(-x)));
                }
                *reinterpret_cast<half4*>(smem + cl * 256 + (rl0 ^ ((cl & 31) << 3))) = pk;
            }
        }
        __syncthreads();
#pragma unroll
        for (int p = 0; p < 16; ++p) {
            const int chunk = p * 512 + tid;
            const int cl = chunk >> 5, scn = chunk & 31;
            half8 v = *reinterpret_cast<const half8*>(smem + cl * 256 + ((scn ^ (cl & 31)) << 3));
            *reinterpret_cast<half8*>(vT + ((size_t)bb * INTER + cI + cl) * SEQ + sloc + scn * 8) = v;
        }
    } else {
        if (wn < 2) {
#pragma unroll
            for (int mt = 0; mt < 8; ++mt) {
#pragma unroll
                for (int nt = 0; nt < 4; ++nt) {
                    const int cq = wn * 64 + nt * 16 + l16;
                    const float qgv = qg[cq], kgv = kg[cq];
#pragma unroll
                    for (int i2 = 0; i2 < 4; ++i2) {
                        const int row = m0 + wm * 128 + mt * 16 + quad * 4 + i2;
                        float x = acc[mt][nt][i2];
                        float y = x / (1.0f + __expf(-x));
                        q[(size_t)row * DK + cq] = (_Float16)(y * qgv);
                        k[(size_t)row * DK + cq] = (_Float16)(y * kgv);
                    }
                }
            }
        }
    }
}

// ---------------------------------------------------------------- scores + softmax -> P (f16)
// R4: P written via LDS staging (16x2048 tile, +8 pad) -> coalesced 16B stores
// instead of 128 scalar 2B global stores per thread.
__global__ __launch_bounds__(256) void scores_kernel(
    const _Float16* __restrict__ q, const _Float16* __restrict__ k,
    const int* __restrict__ mask, const float* __restrict__ scales,
    _Float16* __restrict__ P)
{
    __shared__ _Float16 ps[16 * 2056];   // 16 rows, stride 2056 (bank-spread pad)
    __shared__ float redmax[4][16];
    __shared__ float redsum[4][16];
    const int f = blockIdx.x;
    const int xcd = f & 7, i = f >> 3;          // i: 0..63
    const int b = xcd >> 1;
    const int m0 = ((xcd & 1) * 64 + i) * 16;
    const int tid = threadIdx.x;
    const int wave = tid >> 6, lane = tid & 63, quad = lane >> 4, l16 = lane & 15;
    const float scale = scales[b];

    half8 aq[4];
    const _Float16* qrow = q + (b * SEQ + m0 + l16) * DK + quad * 8;
#pragma unroll
    for (int kk = 0; kk < 4; ++kk) aq[kk] = *reinterpret_cast<const half8*>(qrow + kk * 32);

    floatx4 sc[32];
#pragma unroll
    for (int nt = 0; nt < 32; ++nt) {
        int n0 = nt * 64 + wave * 16;
        const _Float16* krow = k + (b * SEQ + n0 + l16) * DK + quad * 8;
        floatx4 acc = {};
#pragma unroll
        for (int kk = 0; kk < 4; ++kk) {
            half8 bq = *reinterpret_cast<const half8*>(krow + kk * 32);
            acc = __builtin_amdgcn_mfma_f32_16x16x32_f16(aq[kk], bq, acc, 0, 0, 0);
        }
        sc[nt] = acc;
    }

    const float rs = 0.08838834764831845f * scale;
    const float mval = -1e12f * scale;
    float rmax[4] = {-3.4e38f, -3.4e38f, -3.4e38f, -3.4e38f};
#pragma unroll
    for (int nt = 0; nt < 32; ++nt) {
        int ncol = nt * 64 + wave * 16 + l16;
        bool mok = mask[b * SEQ + ncol] != 0;
#pragma unroll
        for (int i2 = 0; i2 < 4; ++i2) {
            float s = mok ? sc[nt][i2] * rs : mval;
            sc[nt][i2] = s;
            rmax[i2] = fmaxf(rmax[i2], s);
        }
    }
#pragma unroll
    for (int i2 = 0; i2 < 4; ++i2) {
#pragma unroll
        for (int off = 1; off < 16; off <<= 1)
            rmax[i2] = fmaxf(rmax[i2], __shfl_xor(rmax[i2], off, 64));
    }
    if (l16 == 0) {
#pragma unroll
        for (int i2 = 0; i2 < 4; ++i2) redmax[wave][quad * 4 + i2] = rmax[i2];
    }
    __syncthreads();
#pragma unroll
    for (int i2 = 0; i2 < 4; ++i2) {
        int r = quad * 4 + i2;
        rmax[i2] = fmaxf(fmaxf(redmax[0][r], redmax[1][r]), fmaxf(redmax[2][r], redmax[3][r]));
    }
    float rsum[4] = {0.f, 0.f, 0.f, 0.f};
#pragma unroll
    for (int nt = 0; nt < 32; ++nt) {
#pragma unroll
        for (int i2 = 0; i2 < 4; ++i2) {
            float e = __expf(sc[nt][i2] - rmax[i2]);
            sc[nt][i2] = e;
            rsum[i2] += e;
        }
    }
#pragma unroll
    for (int i2 = 0; i2 < 4; ++i2) {
#pragma unroll
        for (int off = 1; off < 16; off <<= 1) rsum[i2] += __shfl_xor(rsum[i2], off, 64);
    }
    if (l16 == 0) {
#pragma unroll
        for (int i2 = 0; i2 < 4; ++i2) redsum[wave][quad * 4 + i2] = rsum[i2];
    }
    __syncthreads();
#pragma unroll
    for (int i2 = 0; i2 < 4; ++i2) {
        int r = quad * 4 + i2;
        float tot = redsum[0][r] + redsum[1][r] + redsum[2][r] + redsum[3][r];
        float inv = 1.0f / tot;
#pragma unroll
        for (int nt = 0; nt < 32; ++nt) {
            int ncol = nt * 64 + wave * 16 + l16;
            ps[r * 2056 + ncol] = (_Float16)(sc[nt][i2] * inv);
        }
    }
    __syncthreads();
    // coalesced write-out: 4096 chunks of 16B, 16 per thread
    _Float16* Pb = P + ((size_t)b * SEQ + m0) * SEQ;
#pragma unroll
    for (int p = 0; p < 16; ++p) {
        const int chunk = p * 256 + tid;
        const int row = chunk >> 8, c8 = chunk & 255;
        half8 v = *reinterpret_cast<const half8*>(ps + row * 2056 + c8 * 8);
        *reinterpret_cast<half8*>(Pb + (size_t)row * SEQ + c8 * 8) = v;
    }
}

// ---------------------------------------------------------------- PV: u <- u .* (P @ v)  (32x32 MFMA)
__global__ __launch_bounds__(256) void pv_kernel(
    const _Float16* __restrict__ P, const _Float16* __restrict__ vT,
    _Float16* __restrict__ u)
{
    __shared__ _Float16 smem[24576];
    TileCtx t = make_ctx();
    const int f = blockIdx.x;
    const int xcd = f & 7, i = f >> 3;
    const int b = i / 24, j = i % 24;
    const int m0 = (xcd * 2 + (j & 1)) * 128;
    const int n0 = (j >> 1) * 128;
    const _Float16* Pb  = P  + (size_t)b * SEQ * SEQ;
    const _Float16* vTb = vT + (size_t)b * INTER * SEQ;

    floatx16 acc[2][2] = {};
    gemm_mainloop_3s32(t, Pb + (size_t)m0 * SEQ, SEQ, vTb + (size_t)n0 * SEQ, SEQ, SEQ, smem, acc);

    // C/D 32x32: col = lane&31, row = (reg&3) + 8*(reg>>2) + 4*(lane>>5)
#pragma unroll
    for (int mt = 0; mt < 2; ++mt) {
#pragma unroll
        for (int nt = 0; nt < 2; ++nt) {
            int col = n0 + t.wn + nt * 32 + t.l31;
#pragma unroll
            for (int reg = 0; reg < 16; ++reg) {
                int row = m0 + t.wm + mt * 32 + (reg & 3) + 8 * (reg >> 2) + 4 * t.half;
                size_t gidx = ((size_t)(b * SEQ + row)) * INTER + col;
                float uv = (float)u[gidx];
                u[gidx] = (_Float16)(acc[mt][nt][reg] * uv);
            }
        }
    }
}

// ---------------------------------------------------------------- GEMM2: out = t @ Wo (fp32 out, 32x32 MFMA)
__global__ __launch_bounds__(256) void gemm2_kernel(
    const _Float16* __restrict__ tin, const _Float16* __restrict__ WoT,
    float* __restrict__ out)
{
    __shared__ _Float16 smem[24576];
    TileCtx t = make_ctx();
    const int f = blockIdx.x;
    const int xcd = f & 7, i = f >> 3;
    const int m0 = ((xcd << 3) | (i & 7)) * 128;
    const int n0 = (i >> 3) * 128;

    floatx16 acc[2][2] = {};
    gemm_mainloop_3s32(t, tin + (size_t)m0 * INTER, INTER, WoT + (size_t)n0 * INTER, INTER, INTER, smem, acc);

#pragma unroll
    for (int mt = 0; mt < 2; ++mt) {
#pragma unroll
        for (int nt = 0; nt < 2; ++nt) {
            int col = n0 + t.wn + nt * 32 + t.l31;
#pragma unroll
            for (int reg = 0; reg < 16; ++reg) {
                int row = m0 + t.wm + mt * 32 + (reg & 3) + 8 * (reg >> 2) + 4 * t.half;
                out[(size_t)row * HID + col] = acc[mt][nt][reg];
            }
        }
    }
}

// ---------------------------------------------------------------- launch
extern "C" void kernel_launch(void* const* d_in, const int* in_sizes, int n_in,
                              void* d_out, int out_size, void* d_ws, size_t ws_size,
                              hipStream_t stream) {
    const float* H    = (const float*)d_in[0];
    const float* Wi   = (const float*)d_in[1];
    const float* Wo   = (const float*)d_in[2];
    const float* qg   = (const float*)d_in[3];
    const float* kg   = (const float*)d_in[4];
    const int*   mask = (const int*)d_in[5];
    float* out = (float*)d_out;

    char* base = (char*)d_ws;
    size_t off = 0;
    auto alloc = [&](size_t bytes) { void* p = base + off; off = (off + bytes + 255) & ~(size_t)255; return p; };
    _Float16* Hb   = (_Float16*)alloc((size_t)MROWS * HID * 2);
    _Float16* WiT  = (_Float16*)alloc((size_t)NTOTP * HID * 2);   // padded rows [NTOT,NTOTP) = 0
    _Float16* WoT  = (_Float16*)alloc((size_t)HID * INTER * 2);
    _Float16* u    = (_Float16*)alloc((size_t)MROWS * INTER * 2);   // becomes t in-place after pv
    _Float16* vT   = (_Float16*)alloc((size_t)BATCH * INTER * SEQ * 2);
    _Float16* q    = (_Float16*)alloc((size_t)MROWS * DK * 2);
    _Float16* k    = (_Float16*)alloc((size_t)MROWS * DK * 2);
    _Float16* P    = (_Float16*)alloc((size_t)BATCH * SEQ * SEQ * 2);
    float*    scales = (float*)alloc(4 * sizeof(float));

    // merged preps: cast H + transpose Wi + transpose Wo + mask scales
    prep_kernel<<<6724, 256, 0, stream>>>(H, Hb, Wi, WiT, Wo, WoT, mask, scales);
    // GEMM1: M=8192 N=3328(padded) K=768, 256x256 tiles, 8 XCD x 4 M x 13 N
    gemm1_kernel<<<416, 512, 0, stream>>>(Hb, WiT, qg, kg, u, vT, q, k);
    // scores + softmax -> P
    scores_kernel<<<512, 256, 0, stream>>>(q, k, mask, scales, P);
    // PV: per batch M=2048 N=1536 K=2048
    pv_kernel<<<768, 256, 0, stream>>>(P, vT, u);
    // GEMM2: M=8192 N=768 K=1536
    gemm2_kernel<<<384, 256, 0, stream>>>(u, WoT, out);
}

// Round 5
// 293.117 us; speedup vs baseline: 1.2234x; 1.0115x over previous
//
#include <hip/hip_runtime.h>
#include <hip/hip_bf16.h>
#include <math.h>

// Problem constants
#define BATCH 4
#define SEQ   2048
#define HID   768
#define INTER 1536
#define DK    128
#define NTOT  3200      // 2*INTER + DK
#define NTOTP 3328      // padded to 13*256 for 256-wide gemm1 tiles
#define MROWS 8192      // BATCH*SEQ
#define LN512 6.2383246250395075f

typedef _Float16 half8   __attribute__((ext_vector_type(8)));
typedef _Float16 half4   __attribute__((ext_vector_type(4)));
typedef float    floatx4 __attribute__((ext_vector_type(4)));
typedef float    floatx16 __attribute__((ext_vector_type(16)));

typedef const __attribute__((address_space(1))) unsigned int* gas1_t;
typedef __attribute__((address_space(3))) unsigned int* las3_t;

static __device__ __forceinline__ void load16(const _Float16* g, _Float16* l) {
    __builtin_amdgcn_global_load_lds((gas1_t)g, (las3_t)l, 16, 0, 0);
}
#define WAIT_VM(N)    asm volatile("s_waitcnt vmcnt(" #N ")" ::: "memory")
#define WAIT_LGKM0()  asm volatile("s_waitcnt lgkmcnt(0)" ::: "memory")
#define BARRIER_RAW() asm volatile("s_barrier" ::: "memory")
// direct global->VGPR 16B load; "memory" clobber keeps gload_lds builtins from
// migrating across (vmcnt accounting depends on exact issue order)
#define GLOAD16(dst, ptr) \
    asm volatile("global_load_dwordx4 %0, %1, off" : "=v"(dst) : "v"(ptr) : "memory")

// ---------------------------------------------------------------- merged prep kernel
// grid 6724 = 3072 (cast H) + 2496 (trans Wi) + 1152 (trans Wo) + 4 (mask scales)
__global__ __launch_bounds__(256) void prep_kernel(
    const float* __restrict__ H, _Float16* __restrict__ Hb,
    const float* __restrict__ Wi, _Float16* __restrict__ WiT,
    const float* __restrict__ Wo, _Float16* __restrict__ WoT,
    const int* __restrict__ mask, float* __restrict__ scales)
{
    __shared__ _Float16 tile[32][33];
    __shared__ int sh[256];
    const int bid = blockIdx.x, tid = threadIdx.x;
    if (bid < 3072) {
        const int i = (bid * 256 + tid) * 8;
        float4 a = *reinterpret_cast<const float4*>(H + i);
        float4 b = *reinterpret_cast<const float4*>(H + i + 4);
        half8 h = {(_Float16)a.x, (_Float16)a.y, (_Float16)a.z, (_Float16)a.w,
                   (_Float16)b.x, (_Float16)b.y, (_Float16)b.z, (_Float16)b.w};
        *reinterpret_cast<half8*>(Hb + i) = h;
    } else if (bid < 3072 + 2496) {
        const int l = bid - 3072;
        const int c0 = (l % 104) * 32, r0 = (l / 104) * 32;
        const int tx = tid & 31, ty = tid >> 5;
#pragma unroll
        for (int j = 0; j < 32; j += 8)
            tile[tx][ty + j] = (c0 + tx < NTOT)
                ? (_Float16)Wi[(size_t)(r0 + ty + j) * NTOT + c0 + tx]
                : (_Float16)0.0f;
        __syncthreads();
#pragma unroll
        for (int j = 0; j < 32; j += 8)
            WiT[(size_t)(c0 + ty + j) * HID + r0 + tx] = tile[ty + j][tx];
    } else if (bid < 3072 + 2496 + 1152) {
        const int l = bid - (3072 + 2496);
        const int c0 = (l % 24) * 32, r0 = (l / 24) * 32;
        const int tx = tid & 31, ty = tid >> 5;
#pragma unroll
        for (int j = 0; j < 32; j += 8)
            tile[tx][ty + j] = (_Float16)Wo[(size_t)(r0 + ty + j) * HID + c0 + tx];
        __syncthreads();
#pragma unroll
        for (int j = 0; j < 32; j += 8)
            WoT[(size_t)(c0 + ty + j) * INTER + r0 + tx] = tile[ty + j][tx];
    } else {
        const int b = bid - (3072 + 2496 + 1152);
        int s = 0;
        for (int i = tid; i < SEQ; i += 256) s += mask[b * SEQ + i];
        sh[tid] = s;
        __syncthreads();
        for (int off = 128; off > 0; off >>= 1) {
            if (tid < off) sh[tid] += sh[tid + off];
            __syncthreads();
        }
        if (tid == 0) scales[b] = logf((float)sh[0]) / LN512;
    }
}

// ---------------------------------------------------------------- shared tile ctx (256-thread kernels)
struct TileCtx {
    int tid, wave, lane, quad, l16, l31, half, wm, wn, c0, c1;
};
static __device__ __forceinline__ TileCtx make_ctx() {
    TileCtx t;
    t.tid = threadIdx.x;
    t.wave = t.tid >> 6; t.lane = t.tid & 63;
    t.quad = t.lane >> 4; t.l16 = t.lane & 15;
    t.l31 = t.lane & 31;  t.half = t.lane >> 5;
    t.wm = (t.wave & 1) * 64;
    t.wn = (t.wave >> 1) * 64;
    t.c0 = t.tid;
    t.c1 = t.tid + 256;
    return t;
}

// ================================================================ mainloop B: 32x32x16 (gemm2)
// R2-proven: 3-slot/48KB/1-barrier skeleton; swizzle s32(r) = ((r>>1)^(r>>3))&3.
static __device__ __forceinline__ void gemm_mainloop_3s32(
    const TileCtx& t,
    const _Float16* __restrict__ Ag, int lda,
    const _Float16* __restrict__ Bg, int ldb,
    int K, _Float16* smem, floatx16 acc[2][2])
{
    const int r0i = t.c0 >> 2, s0 = (((r0i >> 1) ^ (r0i >> 3)) & 3);
    const int r1i = t.c1 >> 2, s1 = (((r1i >> 1) ^ (r1i >> 3)) & 3);
    const int ak0 = ((t.c0 & 3) ^ s0) * 8;
    const int ak1 = ((t.c1 & 3) ^ s1) * 8;
    const _Float16* a0 = Ag + (size_t)r0i * lda + ak0;
    const _Float16* a1 = Ag + (size_t)r1i * lda + ak1;
    const _Float16* b0 = Bg + (size_t)r0i * ldb + ak0;
    const _Float16* b1 = Bg + (size_t)r1i * ldb + ak1;
    _Float16* Asl = smem + t.c0 * 8;
    _Float16* Bsl = smem + 12288 + t.c0 * 8;
    const int nIter = K >> 5;

    const int fsw = ((t.l31 >> 1) ^ (t.l31 >> 3)) & 3;

    load16(a0, Asl);        load16(a1, Asl + 2048);
    load16(b0, Bsl);        load16(b1, Bsl + 2048);
    if (nIter > 1) {
        load16(a0 + 32, Asl + 4096); load16(a1 + 32, Asl + 6144);
        load16(b0 + 32, Bsl + 4096); load16(b1 + 32, Bsl + 6144);
    }

    int sc = 0, sp = 2;
    for (int k = 0; k < nIter; ++k) {
        if (k + 1 < nIter) { WAIT_VM(4); } else { WAIT_VM(0); }
        BARRIER_RAW();
        if (k + 2 < nIter) {
            const int off = sp * 4096;
            const int k0 = (k + 2) << 5;
            load16(a0 + k0, Asl + off); load16(a1 + k0, Asl + off + 2048);
            load16(b0 + k0, Bsl + off); load16(b1 + k0, Bsl + off + 2048);
        }
        const _Float16* Ab = smem + sc * 4096;
        const _Float16* Bb = smem + 12288 + sc * 4096;
        half8 af[2][2], bf[2][2];   // [tile][kstep]
#pragma unroll
        for (int mt = 0; mt < 2; ++mt)
#pragma unroll
            for (int h = 0; h < 2; ++h)
                af[mt][h] = *reinterpret_cast<const half8*>(
                    Ab + (t.wm + mt * 32 + t.l31) * 32 + (((h * 2 + t.half) ^ fsw) * 8));
#pragma unroll
        for (int nt = 0; nt < 2; ++nt)
#pragma unroll
            for (int h = 0; h < 2; ++h)
                bf[nt][h] = *reinterpret_cast<const half8*>(
                    Bb + (t.wn + nt * 32 + t.l31) * 32 + (((h * 2 + t.half) ^ fsw) * 8));
#pragma unroll
        for (int h = 0; h < 2; ++h)
#pragma unroll
            for (int mt = 0; mt < 2; ++mt)
#pragma unroll
                for (int nt = 0; nt < 2; ++nt)
                    acc[mt][nt] = __builtin_amdgcn_mfma_f32_32x32x16_f16(af[mt][h], bf[nt][h], acc[mt][nt], 0, 0, 0);
        WAIT_LGKM0();
        sc = (sc == 2) ? 0 : sc + 1;
        sp = (sp == 2) ? 0 : sp + 1;
    }
}

// ---------------------------------------------------------------- GEMM1: silu(H@Wi) -> u, vT, q, k
// 256x256 tile, 512 threads (8 waves 2Mx4N), wave tile 128x64, BK=32,
// 4 LDS slots (128KB) distance-3 prefetch, ONE barrier + counted vmcnt(8) per
// K-tile. Grid 416 = 8 XCD x 4 Mtile x 13 Ntile.
__global__ __launch_bounds__(512, 2) void gemm1_kernel(
    const _Float16* __restrict__ Hb, const _Float16* __restrict__ WiT,
    const float* __restrict__ qg, const float* __restrict__ kg,
    _Float16* __restrict__ u, _Float16* __restrict__ vT,
    _Float16* __restrict__ q, _Float16* __restrict__ k)
{
    __shared__ _Float16 smem[65536];   // 4 slots x 32KB (A 16KB + B 16KB)
    const int tid = threadIdx.x;
    const int lane = tid & 63, wave = tid >> 6;
    const int quad = lane >> 4, l16 = lane & 15;
    const int wm = wave >> 2, wn = wave & 3;          // 2M x 4N waves

    const int f = blockIdx.x;
    const int xcd = f & 7, i = f >> 3;                // i: 0..51
    const int m0 = (xcd * 4 + (i & 3)) * 256;
    const int ntile = i >> 2;                         // 0..12
    const int n0 = ntile * 256;

    const _Float16* Ag = Hb  + (size_t)m0 * HID;
    const _Float16* Bg = WiT + (size_t)n0 * HID;

    const int rA = tid >> 2;
    const int csw = ((tid & 3) ^ ((rA >> 1) & 3)) * 8;
    const _Float16* pa0 = Ag + (size_t)rA * HID + csw;
    const _Float16* pa1 = pa0 + (size_t)128 * HID;
    const _Float16* pb0 = Bg + (size_t)rA * HID + csw;
    const _Float16* pb1 = pb0 + (size_t)128 * HID;

    const int sw8 = (l16 >> 1) & 3;
    const int qs  = (quad ^ sw8) * 8;
    const int aoff = (wm * 128 + l16) * 32 + qs;
    const int boff = 8192 + (wn * 64 + l16) * 32 + qs;

    floatx4 acc[8][4] = {};

    const int nKt = HID / 32;   // 24

    // prologue: stage tiles 0..2 into slots 0..2
#pragma unroll
    for (int pt = 0; pt < 3; ++pt) {
        _Float16* ld = smem + pt * 16384 + tid * 8;
        const int ko = pt * 32;
        load16(pa0 + ko, ld);
        load16(pa1 + ko, ld + 4096);
        load16(pb0 + ko, ld + 8192);
        load16(pb1 + ko, ld + 12288);
    }
    WAIT_VM(8);
    BARRIER_RAW();

    for (int t = 0; t < nKt; ++t) {
        const _Float16* sl = smem + (t & 3) * 16384;
        if (t + 3 < nKt) {
            _Float16* ld = smem + ((t + 3) & 3) * 16384 + tid * 8;
            const int ko = (t + 3) * 32;
            load16(pa0 + ko, ld);        load16(pa1 + ko, ld + 4096);
            load16(pb0 + ko, ld + 8192); load16(pb1 + ko, ld + 12288);
        }
        half8 af[8], bf[4];
#pragma unroll
        for (int mt = 0; mt < 8; ++mt)
            af[mt] = *reinterpret_cast<const half8*>(sl + aoff + mt * 512);
#pragma unroll
        for (int nt = 0; nt < 4; ++nt)
            bf[nt] = *reinterpret_cast<const half8*>(sl + boff + nt * 512);
        __builtin_amdgcn_s_setprio(1);
#pragma unroll
        for (int mt = 0; mt < 8; ++mt)
#pragma unroll
            for (int nt = 0; nt < 4; ++nt)
                acc[mt][nt] = __builtin_amdgcn_mfma_f32_16x16x32_f16(af[mt], bf[nt], acc[mt][nt], 0, 0, 0);
        __builtin_amdgcn_s_setprio(0);
        if (t <= nKt - 4)      { WAIT_VM(8); }
        else if (t == nKt - 3) { WAIT_VM(4); }
        else if (t == nKt - 2) { WAIT_VM(0); }
        BARRIER_RAW();
    }
    __syncthreads();

    // ---------------- epilogue: silu + region-specific stores
    if (ntile < 6) {
#pragma unroll
        for (int mt = 0; mt < 8; ++mt) {
#pragma unroll
            for (int nt = 0; nt < 4; ++nt) {
                const int col = n0 + wn * 64 + nt * 16 + l16;
#pragma unroll
                for (int i2 = 0; i2 < 4; ++i2) {
                    const int row = m0 + wm * 128 + mt * 16 + quad * 4 + i2;
                    float x = acc[mt][nt][i2];
                    float y = x / (1.0f + __expf(-x));
                    u[(size_t)row * INTER + col] = (_Float16)y;
                }
            }
        }
    } else if (ntile < 12) {
        const int bb = m0 >> 11, sloc = m0 & (SEQ - 1), cI = n0 - INTER;
#pragma unroll
        for (int mt = 0; mt < 8; ++mt) {
#pragma unroll
            for (int nt = 0; nt < 4; ++nt) {
                const int cl  = wn * 64 + nt * 16 + l16;
                const int rl0 = wm * 128 + mt * 16 + quad * 4;
                half4 pk;
#pragma unroll
                for (int i2 = 0; i2 < 4; ++i2) {
                    float x = acc[mt][nt][i2];
                    pk[i2] = (_Float16)(x / (1.0f + __expf(-x)));
                }
                *reinterpret_cast<half4*>(smem + cl * 256 + (rl0 ^ ((cl & 31) << 3))) = pk;
            }
        }
        __syncthreads();
#pragma unroll
        for (int p = 0; p < 16; ++p) {
            const int chunk = p * 512 + tid;
            const int cl = chunk >> 5, scn = chunk & 31;
            half8 v = *reinterpret_cast<const half8*>(smem + cl * 256 + ((scn ^ (cl & 31)) << 3));
            *reinterpret_cast<half8*>(vT + ((size_t)bb * INTER + cI + cl) * SEQ + sloc + scn * 8) = v;
        }
    } else {
        if (wn < 2) {
#pragma unroll
            for (int mt = 0; mt < 8; ++mt) {
#pragma unroll
                for (int nt = 0; nt < 4; ++nt) {
                    const int cq = wn * 64 + nt * 16 + l16;
                    const float qgv = qg[cq], kgv = kg[cq];
#pragma unroll
                    for (int i2 = 0; i2 < 4; ++i2) {
                        const int row = m0 + wm * 128 + mt * 16 + quad * 4 + i2;
                        float x = acc[mt][nt][i2];
                        float y = x / (1.0f + __expf(-x));
                        q[(size_t)row * DK + cq] = (_Float16)(y * qgv);
                        k[(size_t)row * DK + cq] = (_Float16)(y * kgv);
                    }
                }
            }
        }
    }
}

// ---------------------------------------------------------------- scores + softmax -> P_frag (f16)
// R5: P written in MFMA-fragment chunk-major layout P_frag[b][n/8][m][8] so pv
// can load A-fragments directly global->VGPR (coalesced 512B segments).
__global__ __launch_bounds__(256) void scores_kernel(
    const _Float16* __restrict__ q, const _Float16* __restrict__ k,
    const int* __restrict__ mask, const float* __restrict__ scales,
    _Float16* __restrict__ P)
{
    __shared__ _Float16 ps[16 * 2056];   // 16 rows, stride 2056 (bank-spread pad)
    __shared__ float redmax[4][16];
    __shared__ float redsum[4][16];
    const int f = blockIdx.x;
    const int xcd = f & 7, i = f >> 3;          // i: 0..63
    const int b = xcd >> 1;
    const int m0 = ((xcd & 1) * 64 + i) * 16;
    const int tid = threadIdx.x;
    const int wave = tid >> 6, lane = tid & 63, quad = lane >> 4, l16 = lane & 15;
    const float scale = scales[b];

    half8 aq[4];
    const _Float16* qrow = q + (b * SEQ + m0 + l16) * DK + quad * 8;
#pragma unroll
    for (int kk = 0; kk < 4; ++kk) aq[kk] = *reinterpret_cast<const half8*>(qrow + kk * 32);

    floatx4 sc[32];
#pragma unroll
    for (int nt = 0; nt < 32; ++nt) {
        int n0 = nt * 64 + wave * 16;
        const _Float16* krow = k + (b * SEQ + n0 + l16) * DK + quad * 8;
        floatx4 acc = {};
#pragma unroll
        for (int kk = 0; kk < 4; ++kk) {
            half8 bq = *reinterpret_cast<const half8*>(krow + kk * 32);
            acc = __builtin_amdgcn_mfma_f32_16x16x32_f16(aq[kk], bq, acc, 0, 0, 0);
        }
        sc[nt] = acc;
    }

    const float rs = 0.08838834764831845f * scale;
    const float mval = -1e12f * scale;
    float rmax[4] = {-3.4e38f, -3.4e38f, -3.4e38f, -3.4e38f};
#pragma unroll
    for (int nt = 0; nt < 32; ++nt) {
        int ncol = nt * 64 + wave * 16 + l16;
        bool mok = mask[b * SEQ + ncol] != 0;
#pragma unroll
        for (int i2 = 0; i2 < 4; ++i2) {
            float s = mok ? sc[nt][i2] * rs : mval;
            sc[nt][i2] = s;
            rmax[i2] = fmaxf(rmax[i2], s);
        }
    }
#pragma unroll
    for (int i2 = 0; i2 < 4; ++i2) {
#pragma unroll
        for (int off = 1; off < 16; off <<= 1)
            rmax[i2] = fmaxf(rmax[i2], __shfl_xor(rmax[i2], off, 64));
    }
    if (l16 == 0) {
#pragma unroll
        for (int i2 = 0; i2 < 4; ++i2) redmax[wave][quad * 4 + i2] = rmax[i2];
    }
    __syncthreads();
#pragma unroll
    for (int i2 = 0; i2 < 4; ++i2) {
        int r = quad * 4 + i2;
        rmax[i2] = fmaxf(fmaxf(redmax[0][r], redmax[1][r]), fmaxf(redmax[2][r], redmax[3][r]));
    }
    float rsum[4] = {0.f, 0.f, 0.f, 0.f};
#pragma unroll
    for (int nt = 0; nt < 32; ++nt) {
#pragma unroll
        for (int i2 = 0; i2 < 4; ++i2) {
            float e = __expf(sc[nt][i2] - rmax[i2]);
            sc[nt][i2] = e;
            rsum[i2] += e;
        }
    }
#pragma unroll
    for (int i2 = 0; i2 < 4; ++i2) {
#pragma unroll
        for (int off = 1; off < 16; off <<= 1) rsum[i2] += __shfl_xor(rsum[i2], off, 64);
    }
    if (l16 == 0) {
#pragma unroll
        for (int i2 = 0; i2 < 4; ++i2) redsum[wave][quad * 4 + i2] = rsum[i2];
    }
    __syncthreads();
#pragma unroll
    for (int i2 = 0; i2 < 4; ++i2) {
        int r = quad * 4 + i2;
        float tot = redsum[0][r] + redsum[1][r] + redsum[2][r] + redsum[3][r];
        float inv = 1.0f / tot;
#pragma unroll
        for (int nt = 0; nt < 32; ++nt) {
            int ncol = nt * 64 + wave * 16 + l16;
            ps[r * 2056 + ncol] = (_Float16)(sc[nt][i2] * inv);
        }
    }
    __syncthreads();
    // frag-layout write-out: chunk c8 (0..255) x row (0..15); row fastest so
    // 16 consecutive lanes store 16 consecutive rows of one chunk = 256B segs
    _Float16* Pfb = P + (size_t)b * SEQ * SEQ;
#pragma unroll
    for (int p = 0; p < 16; ++p) {
        const int chunk = p * 256 + tid;
        const int row = chunk & 15, c8 = chunk >> 4;
        half8 v = *reinterpret_cast<const half8*>(ps + row * 2056 + c8 * 8);
        *reinterpret_cast<half8*>(Pfb + ((size_t)c8 * SEQ + m0 + row) * 8) = v;
    }
}

// ---------------------------------------------------------------- PV iteration (B in LDS, A from global)
static __device__ __forceinline__ void pv_iter(
    const TileCtx& t, int k, _Float16* smem,
    const _Float16* b0, const _Float16* b1,
    const _Float16* pA0, const _Float16* pA1,
    half8 (&afc)[2][2], half8 (&afn)[2][2],
    floatx16 acc[2][2], int fsw)
{
    const _Float16* Bb = smem + (k % 3) * 4096;
    half8 bf[2][2];
#pragma unroll
    for (int nt = 0; nt < 2; ++nt)
#pragma unroll
        for (int h = 0; h < 2; ++h)
            bf[nt][h] = *reinterpret_cast<const half8*>(
                Bb + (t.wn + nt * 32 + t.l31) * 32 + (((h * 2 + t.half) ^ fsw) * 8));
    if (k + 1 < 64) {   // prefetch A(k+1): 4 chunks of 16B, coalesced 512B segs
        const size_t co = (size_t)(k + 1) * 4 * (SEQ * 8);
        GLOAD16(afn[0][0], pA0 + co);
        GLOAD16(afn[0][1], pA0 + co + 2 * (SEQ * 8));
        GLOAD16(afn[1][0], pA1 + co);
        GLOAD16(afn[1][1], pA1 + co + 2 * (SEQ * 8));
    }
    if (k + 2 < 64) {   // stage B(k+2) into slot (k+2)%3 (read at k-1, barrier-safe)
        _Float16* ld = smem + ((k + 2) % 3) * 4096 + t.c0 * 8;
        const int ko = (k + 2) * 32;
        load16(b0 + ko, ld);
        load16(b1 + ko, ld + 2048);
    }
    // drain through B(k+1) and A(k): outstanding after = A(k+1) + B(k+2)
    if (k <= 61)      { WAIT_VM(6); }
    else if (k == 62) { WAIT_VM(4); }
    else              { WAIT_VM(0); }
    __builtin_amdgcn_sched_barrier(0);
    __builtin_amdgcn_s_setprio(1);
#pragma unroll
    for (int h = 0; h < 2; ++h)
#pragma unroll
        for (int mt = 0; mt < 2; ++mt)
#pragma unroll
            for (int nt = 0; nt < 2; ++nt)
                acc[mt][nt] = __builtin_amdgcn_mfma_f32_32x32x16_f16(afc[mt][h], bf[nt][h], acc[mt][nt], 0, 0, 0);
    __builtin_amdgcn_s_setprio(0);
    BARRIER_RAW();
}

// ---------------------------------------------------------------- PV: u <- u .* (P @ v)
// R5: A (P_frag) direct global->VGPR ping-pong; only B (vT) staged in LDS
// (3 slots x 8KB). LDS traffic per K-tile: 48KB -> 24KB.
__global__ __launch_bounds__(256) void pv_kernel(
    const _Float16* __restrict__ Pf, const _Float16* __restrict__ vT,
    _Float16* __restrict__ u)
{
    __shared__ _Float16 smem[12288];   // 3 slots x 8KB (B only)
    TileCtx t = make_ctx();
    const int f = blockIdx.x;
    const int xcd = f & 7, i = f >> 3;
    const int b = i / 24, j = i % 24;
    const int m0 = (xcd * 2 + (j & 1)) * 128;
    const int n0 = (j >> 1) * 128;
    const _Float16* Pfb = Pf + (size_t)b * SEQ * SEQ;   // [256 chunks][2048 rows][8]
    const _Float16* vTb = vT + (size_t)b * INTER * SEQ;

    // B staging addresses (3s32 pattern: 4 threads/row, pre-swizzled source)
    const int r0i = t.c0 >> 2, s0 = (((r0i >> 1) ^ (r0i >> 3)) & 3);
    const int r1i = t.c1 >> 2, s1 = (((r1i >> 1) ^ (r1i >> 3)) & 3);
    const _Float16* b0 = vTb + (size_t)(n0 + r0i) * SEQ + ((t.c0 & 3) ^ s0) * 8;
    const _Float16* b1 = vTb + (size_t)(n0 + r1i) * SEQ + ((t.c1 & 3) ^ s1) * 8;
    _Float16* Bsl = smem + t.c0 * 8;
    const int fsw = ((t.l31 >> 1) ^ (t.l31 >> 3)) & 3;

    // A fragment base pointers (per-lane): row = m0 + wm + mt*32 + l31, chunk half
    const _Float16* pA0 = Pfb + (size_t)t.half * (SEQ * 8)
                        + (size_t)(m0 + t.wm + t.l31) * 8;
    const _Float16* pA1 = pA0 + 32 * 8;

    floatx16 acc[2][2] = {};
    half8 afA[2][2], afB[2][2];

    // prologue: B(0), B(1) staged; A(0) loaded
    load16(b0, Bsl);        load16(b1, Bsl + 2048);
    load16(b0 + 32, Bsl + 4096); load16(b1 + 32, Bsl + 6144);
    GLOAD16(afA[0][0], pA0);
    GLOAD16(afA[0][1], pA0 + 2 * (SEQ * 8));
    GLOAD16(afA[1][0], pA1);
    GLOAD16(afA[1][1], pA1 + 2 * (SEQ * 8));
    WAIT_VM(4);        // B(0),B(1) landed; A(0) still in flight (drained in iter 0)
    BARRIER_RAW();

    for (int k = 0; k < 64; k += 2) {
        pv_iter(t, k,     smem, b0, b1, pA0, pA1, afA, afB, acc, fsw);
        pv_iter(t, k + 1, smem, b0, b1, pA0, pA1, afB, afA, acc, fsw);
    }

    // C/D 32x32: col = lane&31, row = (reg&3) + 8*(reg>>2) + 4*(lane>>5)
#pragma unroll
    for (int mt = 0; mt < 2; ++mt) {
#pragma unroll
        for (int nt = 0; nt < 2; ++nt) {
            int col = n0 + t.wn + nt * 32 + t.l31;
#pragma unroll
            for (int reg = 0; reg < 16; ++reg) {
                int row = m0 + t.wm + mt * 32 + (reg & 3) + 8 * (reg >> 2) + 4 * t.half;
                size_t gidx = ((size_t)(b * SEQ + row)) * INTER + col;
                float uv = (float)u[gidx];
                u[gidx] = (_Float16)(acc[mt][nt][reg] * uv);
            }
        }
    }
}

// ---------------------------------------------------------------- GEMM2: out = t @ Wo (fp32 out, 32x32 MFMA)
__global__ __launch_bounds__(256) void gemm2_kernel(
    const _Float16* __restrict__ tin, const _Float16* __restrict__ WoT,
    float* __restrict__ out)
{
    __shared__ _Float16 smem[24576];
    TileCtx t = make_ctx();
    const int f = blockIdx.x;
    const int xcd = f & 7, i = f >> 3;
    const int m0 = ((xcd << 3) | (i & 7)) * 128;
    const int n0 = (i >> 3) * 128;

    floatx16 acc[2][2] = {};
    gemm_mainloop_3s32(t, tin + (size_t)m0 * INTER, INTER, WoT + (size_t)n0 * INTER, INTER, INTER, smem, acc);

#pragma unroll
    for (int mt = 0; mt < 2; ++mt) {
#pragma unroll
        for (int nt = 0; nt < 2; ++nt) {
            int col = n0 + t.wn + nt * 32 + t.l31;
#pragma unroll
            for (int reg = 0; reg < 16; ++reg) {
                int row = m0 + t.wm + mt * 32 + (reg & 3) + 8 * (reg >> 2) + 4 * t.half;
                out[(size_t)row * HID + col] = acc[mt][nt][reg];
            }
        }
    }
}

// ---------------------------------------------------------------- launch
extern "C" void kernel_launch(void* const* d_in, const int* in_sizes, int n_in,
                              void* d_out, int out_size, void* d_ws, size_t ws_size,
                              hipStream_t stream) {
    const float* H    = (const float*)d_in[0];
    const float* Wi   = (const float*)d_in[1];
    const float* Wo   = (const float*)d_in[2];
    const float* qg   = (const float*)d_in[3];
    const float* kg   = (const float*)d_in[4];
    const int*   mask = (const int*)d_in[5];
    float* out = (float*)d_out;

    char* base = (char*)d_ws;
    size_t off = 0;
    auto alloc = [&](size_t bytes) { void* p = base + off; off = (off + bytes + 255) & ~(size_t)255; return p; };
    _Float16* Hb   = (_Float16*)alloc((size_t)MROWS * HID * 2);
    _Float16* WiT  = (_Float16*)alloc((size_t)NTOTP * HID * 2);   // padded rows [NTOT,NTOTP) = 0
    _Float16* WoT  = (_Float16*)alloc((size_t)HID * INTER * 2);
    _Float16* u    = (_Float16*)alloc((size_t)MROWS * INTER * 2);   // becomes t in-place after pv
    _Float16* vT   = (_Float16*)alloc((size_t)BATCH * INTER * SEQ * 2);
    _Float16* q    = (_Float16*)alloc((size_t)MROWS * DK * 2);
    _Float16* k    = (_Float16*)alloc((size_t)MROWS * DK * 2);
    _Float16* P    = (_Float16*)alloc((size_t)BATCH * SEQ * SEQ * 2);  // P_frag layout
    float*    scales = (float*)alloc(4 * sizeof(float));

    // merged preps: cast H + transpose Wi + transpose Wo + mask scales
    prep_kernel<<<6724, 256, 0, stream>>>(H, Hb, Wi, WiT, Wo, WoT, mask, scales);
    // GEMM1: M=8192 N=3328(padded) K=768, 256x256 tiles, 8 XCD x 4 M x 13 N
    gemm1_kernel<<<416, 512, 0, stream>>>(Hb, WiT, qg, kg, u, vT, q, k);
    // scores + softmax -> P_frag
    scores_kernel<<<512, 256, 0, stream>>>(q, k, mask, scales, P);
    // PV: per batch M=2048 N=1536 K=2048
    pv_kernel<<<768, 256, 0, stream>>>(P, vT, u);
    // GEMM2: M=8192 N=768 K=1536
    gemm2_kernel<<<384, 256, 0, stream>>>(u, WoT, out);
}